// Round 1
// baseline (391.728 us; speedup 1.0000x reference)
//
#include <hip/hip_runtime.h>
#include <hip/hip_bf16.h>
#include <stdint.h>

using u32 = unsigned int;
using u16 = unsigned short;

typedef short bf16x8 __attribute__((ext_vector_type(8)));
typedef float f32x4 __attribute__((ext_vector_type(4)));
typedef u32  u32x4 __attribute__((ext_vector_type(4)));

__device__ __forceinline__ u16 f2bf(float f) {
  u32 u = __builtin_bit_cast(u32, f);
  u32 r = (u + 0x7FFFu + ((u >> 16) & 1u)) >> 16;   // RNE
  return (u16)r;
}

// ---------------------------------------------------------------- repack ----
// wb1  [256][1152] bf16 : k = tap*128+ic, oc 0..127 = R, 128..255 = T
// wb2r [256][1152], wb2t [64][1152] (rows 48..63 zero)
// consts: scale1/shift1 (BN+bias fold), bias2r, bias2t
__global__ __launch_bounds__(256) void repack_kernel(
    const float* wR1, const float* wT1, const float* wR2, const float* wT2,
    const float* bR1, const float* gR, const float* betR, const float* mR, const float* vR,
    const float* bT1, const float* gT, const float* betT, const float* mT, const float* vT,
    const float* bR2, const float* bT2,
    u16* wb1, u16* wb2r, u16* wb2t,
    float* scale1, float* shift1, float* bias2r, float* bias2t)
{
  const int T1 = 256 * 1152, T2 = 256 * 1152;
  if (blockIdx.x == gridDim.x - 1) {
    int t = threadIdx.x;
    float g, v, be, mm, bb;
    if (t < 128) { g = gR[t]; v = vR[t]; be = betR[t]; mm = mR[t]; bb = bR1[t]; }
    else         { g = gT[t-128]; v = vT[t-128]; be = betT[t-128]; mm = mT[t-128]; bb = bT1[t-128]; }
    float sc = g * rsqrtf(v + 1e-5f);
    scale1[t] = sc;
    shift1[t] = (bb - mm) * sc + be;
    bias2r[t] = bR2[t];
    if (t < 64) bias2t[t] = (t < 48) ? bT2[t] : 0.0f;
    return;
  }
  int idx = blockIdx.x * 256 + threadIdx.x;
  if (idx < T1) {
    int oc = idx / 1152, k = idx - oc * 1152;
    int tap = k >> 7, ic = k & 127;
    float w = (oc < 128) ? wR1[(oc * 128 + ic) * 9 + tap]
                         : wT1[((oc - 128) * 128 + ic) * 9 + tap];
    wb1[idx] = f2bf(w);
  } else if (idx < T1 + T2) {
    int r = idx - T1;
    int oc = r / 1152, k = r - oc * 1152;
    int tap = k >> 7, ic = k & 127;
    wb2r[r] = f2bf(wR2[(oc * 128 + ic) * 9 + tap]);
  } else {
    int r = idx - T1 - T2;
    int oc = r / 1152, k = r - oc * 1152;
    int tap = k >> 7, ic = k & 127;
    wb2t[r] = f2bf((oc < 48) ? wT2[(oc * 128 + ic) * 9 + tap] : 0.0f);
  }
}

// ------------------------------------------------------ NCHW -> NHWC bf16 ---
__global__ __launch_bounds__(256) void transpose_kernel(const float* feat, u16* feat_t)
{
  __shared__ float tile[128 * 33];
  int b = blockIdx.x >> 5, y = blockIdx.x & 31;
  int t = threadIdx.x;
  const float* src = feat + (size_t)(b * 128) * 1024 + y * 32;  // + ic*1024 + x
#pragma unroll
  for (int q = 0; q < 16; q++) {
    int idx = q * 256 + t;
    int ic = idx >> 5, x = idx & 31;
    tile[ic * 33 + x] = src[(size_t)ic * 1024 + x];
  }
  __syncthreads();
  u16* dst = feat_t + (size_t)((b * 32 + y) * 32) * 128;
#pragma unroll
  for (int q = 0; q < 16; q++) {
    int idx = q * 256 + t;
    int x = idx >> 7, ic = idx & 127;
    dst[x * 128 + ic] = f2bf(tile[ic * 33 + x]);
  }
}

// ---------------------------------------------------------------- im2col ----
// col[p][tap*128+ic], p = b*1024+y*32+x.  One wave per (p,tap) chunk: 128 bf16.
__global__ __launch_bounds__(256) void im2col_kernel(const u16* src, u16* col,
                                                     int srcCstride, int srcCoff)
{
  int gtid = blockIdx.x * 256 + threadIdx.x;
  int cid = gtid >> 6, lane = gtid & 63;
  int p = cid / 9, tap = cid - p * 9;
  int b = p >> 10, y = (p >> 5) & 31, x = p & 31;
  int sy = y + (tap / 3) - 1, sx = x + (tap % 3) - 1;
  u32 val = 0;
  if (sy >= 0 && sy < 32 && sx >= 0 && sx < 32) {
    int sp = b * 1024 + sy * 32 + sx;
    val = *reinterpret_cast<const u32*>(src + (size_t)sp * srcCstride + srcCoff + lane * 2);
  }
  *reinterpret_cast<u32*>(col + (size_t)p * 1152 + tap * 128 + lane * 2) = val;
}

// ------------------------------------------------------------------ GEMM ----
// C[M][N] = A[M][K] * Bt[N][K]^T.  BM=128 BN=64 BK=32, 4 waves (2x2), each wave
// 64x32 via 4x2 mfma_f32_16x16x32_bf16.  LDS row stride 56 (112B, 16B-aligned,
// <=2-way bank aliasing).  EPI 0: BN-affine + SiLU -> bf16.  EPI 1: +bias -> f32.
template <int EPI>
__global__ __launch_bounds__(256) void gemm_kernel(
    const u16* __restrict__ A, const u16* __restrict__ Bt, void* Cout,
    int K, int ldC, int Ntrue, const float* __restrict__ c0, const float* __restrict__ c1)
{
  __shared__ u16 As[128 * 56];
  __shared__ u16 Bs[64 * 56];
  int t = threadIdx.x;
  int lane = t & 63, wid = t >> 6;
  int wm = wid >> 1, wn = wid & 1;
  int Mbase = blockIdx.x * 128, Nbase = blockIdx.y * 64;
  f32x4 acc[4][2] = {};
  int nk = K >> 5;
  for (int kt = 0; kt < nk; kt++) {
    __syncthreads();
#pragma unroll
    for (int q = 0; q < 2; q++) {      // A tile: 128 rows x 32 k
      int cid = q * 256 + t;
      int row = cid >> 2, kc = cid & 3;
      u32x4 v = *reinterpret_cast<const u32x4*>(A + (size_t)(Mbase + row) * K + kt * 32 + kc * 8);
      *reinterpret_cast<u32x4*>(&As[row * 56 + kc * 8]) = v;
    }
    {                                   // B tile: 64 rows x 32 k
      int row = t >> 2, kc = t & 3;
      u32x4 v = *reinterpret_cast<const u32x4*>(Bt + (size_t)(Nbase + row) * K + kt * 32 + kc * 8);
      *reinterpret_cast<u32x4*>(&Bs[row * 56 + kc * 8]) = v;
    }
    __syncthreads();
    bf16x8 af[4], bfr[2];
    int ko = (lane >> 4) * 8;
#pragma unroll
    for (int mt = 0; mt < 4; mt++)
      af[mt] = *reinterpret_cast<const bf16x8*>(&As[(wm * 64 + mt * 16 + (lane & 15)) * 56 + ko]);
#pragma unroll
    for (int nt = 0; nt < 2; nt++)
      bfr[nt] = *reinterpret_cast<const bf16x8*>(&Bs[(wn * 32 + nt * 16 + (lane & 15)) * 56 + ko]);
#pragma unroll
    for (int mt = 0; mt < 4; mt++)
#pragma unroll
      for (int nt = 0; nt < 2; nt++)
        acc[mt][nt] = __builtin_amdgcn_mfma_f32_16x16x32_bf16(af[mt], bfr[nt], acc[mt][nt], 0, 0, 0);
  }
#pragma unroll
  for (int mt = 0; mt < 4; mt++) {
#pragma unroll
    for (int nt = 0; nt < 2; nt++) {
      int col = Nbase + wn * 32 + nt * 16 + (lane & 15);
#pragma unroll
      for (int r = 0; r < 4; r++) {
        int row = Mbase + wm * 64 + mt * 16 + (lane >> 4) * 4 + r;
        float v = acc[mt][nt][r];
        if (EPI == 0) {
          float y = v * c0[col] + c1[col];
          float h = y / (1.0f + __expf(-y));   // SiLU
          reinterpret_cast<u16*>(Cout)[(size_t)row * ldC + col] = f2bf(h);
        } else {
          if (col < Ntrue)
            reinterpret_cast<float*>(Cout)[(size_t)row * ldC + col] = v + c0[col];
        }
      }
    }
  }
}

// ------------------------------------------------------------- attention ----
// one block per patch (b,i,j); thread = pixel (py,px); two-pass softmax over 64.
__global__ __launch_bounds__(256) void attn_kernel(
    const float* __restrict__ f, const float* __restrict__ rbuf,
    const float* __restrict__ tbuf, float* __restrict__ out)
{
  __shared__ float  r4l[64 * 16];
  __shared__ float4 t4l[64];
  int blk = blockIdx.x;
  int b = blk / 961, rem = blk - b * 961;
  int i = rem / 31, j = rem - i * 31;
  int t = threadIdx.x;
#pragma unroll
  for (int q = 0; q < 4; q++) {     // r4 (scaled by 1/sqrt(C)=0.25)
    int idx = q * 256 + t;
    int n = idx >> 4, c = idx & 15;
    int g = n >> 4, nl = n & 15;
    int ii = i + (g & 1), jj = j + (g >> 1);
    float v = rbuf[(size_t)((b * 32 + ii) * 32 + jj) * 256 + c * 16 + nl];
    r4l[n * 16 + c] = v * 0.25f;
  }
  if (t < 64) {                      // t4
    int n = t, g = n >> 4, nl = n & 15;
    int ii = i + (g & 1), jj = j + (g >> 1);
    const float* tb = tbuf + (size_t)((b * 32 + ii) * 32 + jj) * 48 + nl;
    t4l[n] = make_float4(tb[0], tb[16], tb[32], 0.0f);
  }
  __syncthreads();
  int py = t >> 4, px = t & 15;
  const float* fp = f + ((size_t)(b * 16) * 496 + (i * 16 + py)) * 496 + (j * 16 + px);
  float fr[16];
#pragma unroll
  for (int c = 0; c < 16; c++) fr[c] = fp[(size_t)c * 496 * 496];
  float s[64];
  float m = -1e30f;
#pragma unroll
  for (int n = 0; n < 64; n++) {
    const float4* rp = reinterpret_cast<const float4*>(&r4l[n * 16]);
    float acc = 0.f;
#pragma unroll
    for (int q = 0; q < 4; q++) {
      float4 rv = rp[q];
      acc += fr[q * 4 + 0] * rv.x + fr[q * 4 + 1] * rv.y +
             fr[q * 4 + 2] * rv.z + fr[q * 4 + 3] * rv.w;
    }
    s[n] = acc;
    m = fmaxf(m, acc);
  }
  float l = 0.f, y0 = 0.f, y1 = 0.f, y2 = 0.f;
#pragma unroll
  for (int n = 0; n < 64; n++) {
    float e = __expf(s[n] - m);
    float4 tv = t4l[n];
    l += e;
    y0 += e * tv.x; y1 += e * tv.y; y2 += e * tv.z;
  }
  float inv = __builtin_amdgcn_rcpf(l);
  size_t ob = ((size_t)(b * 3) * 496 + (i * 16 + py)) * 496 + (j * 16 + px);
  out[ob] = y0 * inv;
  out[ob + (size_t)496 * 496] = y1 * inv;
  out[ob + (size_t)2 * 496 * 496] = y2 * inv;
}

// ----------------------------------------------------------------- launch ---
extern "C" void kernel_launch(void* const* d_in, const int* in_sizes, int n_in,
                              void* d_out, int out_size, void* d_ws, size_t ws_size,
                              hipStream_t stream)
{
  const float* f    = (const float*)d_in[0];
  const float* feats= (const float*)d_in[1];
  const float* wR1  = (const float*)d_in[2];
  const float* bR1  = (const float*)d_in[3];
  const float* gR   = (const float*)d_in[4];
  const float* betR = (const float*)d_in[5];
  const float* mR   = (const float*)d_in[6];
  const float* vR   = (const float*)d_in[7];
  const float* wR2  = (const float*)d_in[8];
  const float* bR2  = (const float*)d_in[9];
  const float* wT1  = (const float*)d_in[10];
  const float* bT1  = (const float*)d_in[11];
  const float* gT   = (const float*)d_in[12];
  const float* betT = (const float*)d_in[13];
  const float* mT   = (const float*)d_in[14];
  const float* vT   = (const float*)d_in[15];
  const float* wT2  = (const float*)d_in[16];
  const float* bT2  = (const float*)d_in[17];
  (void)in_sizes; (void)n_in; (void)out_size; (void)ws_size;

  char* ws = (char*)d_ws;
  u16*   wb1    = (u16*)(ws + 0);              //  256*1152*2 = 589824
  u16*   wb2r   = (u16*)(ws + 589824);         //  589824
  u16*   wb2t   = (u16*)(ws + 1179648);        //  147456
  float* scale1 = (float*)(ws + 1327104);      //  256 f
  float* shift1 = scale1 + 256;
  float* bias2r = scale1 + 512;
  float* bias2t = scale1 + 768;
  u16*   feat_t = (u16*)(ws + 1331200);        //  8*1024*128*2 = 2097152
  u16*   hbuf   = (u16*)(ws + 3428352);        //  8192*256*2   = 4194304
  float* rbuf   = (float*)(ws + 7622656);      //  8192*256*4   = 8388608
  float* tbuf   = (float*)(ws + 16011264);     //  8192*48*4    = 1572864
  u16*   colb   = (u16*)(ws + 17584128);       //  8192*1152*2  = 18874368 (reused 3x)

  repack_kernel<<<dim3(2593), dim3(256), 0, stream>>>(
      wR1, wT1, wR2, wT2, bR1, gR, betR, mR, vR, bT1, gT, betT, mT, vT,
      bR2, bT2, wb1, wb2r, wb2t, scale1, shift1, bias2r, bias2t);

  transpose_kernel<<<dim3(256), dim3(256), 0, stream>>>(feats, feat_t);

  // conv1 (R||T fused, 256 oc)
  im2col_kernel<<<dim3(18432), dim3(256), 0, stream>>>(feat_t, colb, 128, 0);
  gemm_kernel<0><<<dim3(64, 4), dim3(256), 0, stream>>>(
      colb, wb1, hbuf, 1152, 256, 256, scale1, shift1);

  // conv2R
  im2col_kernel<<<dim3(18432), dim3(256), 0, stream>>>(hbuf, colb, 256, 0);
  gemm_kernel<1><<<dim3(64, 4), dim3(256), 0, stream>>>(
      colb, wb2r, rbuf, 1152, 256, 256, bias2r, nullptr);

  // conv2T
  im2col_kernel<<<dim3(18432), dim3(256), 0, stream>>>(hbuf, colb, 256, 128);
  gemm_kernel<1><<<dim3(64, 1), dim3(256), 0, stream>>>(
      colb, wb2t, tbuf, 1152, 48, 48, bias2t, nullptr);

  attn_kernel<<<dim3(7688), dim3(256), 0, stream>>>(f, rbuf, tbuf, (float*)d_out);
}

// Round 2
// 320.039 us; speedup vs baseline: 1.2240x; 1.2240x over previous
//
#include <hip/hip_runtime.h>
#include <hip/hip_bf16.h>
#include <stdint.h>
#include <stddef.h>

using u32 = unsigned int;
using u16 = unsigned short;

typedef short bf16x8 __attribute__((ext_vector_type(8)));
typedef _Float16 f16x8 __attribute__((ext_vector_type(8)));
typedef float f32x4 __attribute__((ext_vector_type(4)));
typedef u32  u32x4 __attribute__((ext_vector_type(4)));

__device__ __forceinline__ u16 f2bf(float f) {
  u32 u = __builtin_bit_cast(u32, f);
  u32 r = (u + 0x7FFFu + ((u >> 16) & 1u)) >> 16;   // RNE
  return (u16)r;
}

// ---------------------------------------------------------------- repack ----
// wb1 [256][1152] bf16 (k = tap*128+ic; oc<128=R, else T)
// wb2 [320][1152] bf16 (oc<256 = R2; 256..303 = T2; 304..319 = 0)
// scale1/shift1[256] (BN+bias fold), biasC[320]
__global__ __launch_bounds__(256) void repack_kernel(
    const float* wR1, const float* wT1, const float* wR2, const float* wT2,
    const float* bR1, const float* gR, const float* betR, const float* mR, const float* vR,
    const float* bT1, const float* gT, const float* betT, const float* mT, const float* vT,
    const float* bR2, const float* bT2,
    u16* wb1, u16* wb2, float* scale1, float* shift1, float* biasC)
{
  if (blockIdx.x == 2592) {
    int t = threadIdx.x;
    float g, v, be, mm, bb;
    if (t < 128) { g = gR[t]; v = vR[t]; be = betR[t]; mm = mR[t]; bb = bR1[t]; }
    else         { g = gT[t-128]; v = vT[t-128]; be = betT[t-128]; mm = mT[t-128]; bb = bT1[t-128]; }
    float sc = g * rsqrtf(v + 1e-5f);
    scale1[t] = sc;
    shift1[t] = (bb - mm) * sc + be;
    biasC[t] = bR2[t];
    if (t < 64) biasC[256 + t] = (t < 48) ? bT2[t] : 0.0f;
    return;
  }
  int idx = blockIdx.x * 256 + threadIdx.x;
  if (idx < 294912) {
    int oc = idx / 1152, k = idx - oc * 1152;
    int tap = k >> 7, ic = k & 127;
    float w = (oc < 128) ? wR1[(oc * 128 + ic) * 9 + tap]
                         : wT1[((oc - 128) * 128 + ic) * 9 + tap];
    wb1[idx] = f2bf(w);
  } else {
    int r2 = idx - 294912;
    int oc = r2 / 1152, k = r2 - oc * 1152;
    int tap = k >> 7, ic = k & 127;
    float w;
    if (oc < 256)            w = wR2[(oc * 128 + ic) * 9 + tap];
    else if (oc - 256 < 48)  w = wT2[((oc - 256) * 128 + ic) * 9 + tap];
    else                     w = 0.0f;
    wb2[r2] = f2bf(w);
  }
}

// ------------------------------------------------------ NCHW -> NHWC bf16 ---
__global__ __launch_bounds__(256) void transpose_kernel(const float* feat, u16* feat_t)
{
  __shared__ float tile[128 * 33];
  int b = blockIdx.x >> 5, y = blockIdx.x & 31;
  int t = threadIdx.x;
  const float* src = feat + (size_t)(b * 128) * 1024 + y * 32;
#pragma unroll
  for (int q = 0; q < 16; q++) {
    int idx = q * 256 + t;
    int ic = idx >> 5, x = idx & 31;
    tile[ic * 33 + x] = src[(size_t)ic * 1024 + x];
  }
  __syncthreads();
  u16* dst = feat_t + (size_t)((b * 32 + y) * 32) * 128;
#pragma unroll
  for (int q = 0; q < 16; q++) {
    int idx = q * 256 + t;
    int x = idx >> 7, ic = idx & 127;
    dst[x * 128 + ic] = f2bf(tile[ic * 33 + x]);
  }
}

// -------------------------------------------- implicit-im2col conv GEMM ----
// C[8192][N] = im2col(src)[8192][1152] * Bt[N][1152]^T, 3x3 SAME conv on 32x32.
// BM=128 BN=64 BK=32 (k = tap*128+icr), 4 waves 2x2, mfma 16x16x32_bf16.
// EPI 0: y=v*c0+c1, SiLU, bf16 -> out0[pix][256].
// EPI 1: v+=c0[col]; col<256 -> f16(v*0.125) at out0[pix][(col&15)*16+(col>>4)]
//        col>=256  -> cT=col-256; cT<48: out1[pix][(cT&15)*4+(cT>>4)]=v; else pad=0
template <int SRCC, int EPI>
__global__ __launch_bounds__(256) void conv_gemm_kernel(
    const u16* __restrict__ src, const u16* __restrict__ Bt,
    u16* __restrict__ out0, float* __restrict__ out1,
    const float* __restrict__ c0, const float* __restrict__ c1)
{
  __shared__ u16 As[128 * 40];
  __shared__ u16 Bs[64 * 40];
  int t = threadIdx.x;
  int lane = t & 63, wid = t >> 6;
  int wm = wid >> 1, wn = wid & 1;
  int Mbase = blockIdx.x * 128, Nbase = blockIdx.y * 64;
  int icOff = (EPI == 1 && blockIdx.y == 4) ? 128 : 0;

  // staging precompute (rows q*64 + t>>2, chunk t&3)
  int rA = t >> 2, chA = t & 3;
  int p0 = Mbase + rA, p1 = p0 + 64;
  int y0 = (p0 >> 5) & 31, x0 = p0 & 31;
  int y1 = (p1 >> 5) & 31, x1 = p1 & 31;
  const u16* aSrc0 = src + (size_t)p0 * SRCC + icOff + chA * 8;
  const u16* aSrc1 = src + (size_t)p1 * SRCC + icOff + chA * 8;
  u16* aDst0 = &As[rA * 40 + chA * 8];
  u16* aDst1 = &As[(rA + 64) * 40 + chA * 8];
  const u16* bSrc = Bt + (size_t)(Nbase + rA) * 1152 + chA * 8;
  u16* bDst = &Bs[rA * 40 + chA * 8];

  f32x4 acc[4][2] = {};
  for (int kt = 0; kt < 36; kt++) {
    int tap = kt >> 2, icr = (kt & 3) * 32;
    int dy = tap / 3 - 1, dx = tap - (tap / 3) * 3 - 1;   // uniform -> SALU
    int aoff = (dy * 32 + dx) * SRCC + icr;               // signed!
    __syncthreads();
    u32x4 v0 = {}, v1 = {};
    if ((u32)(y0 + dy) < 32u && (u32)(x0 + dx) < 32u)
      v0 = *reinterpret_cast<const u32x4*>(aSrc0 + (ptrdiff_t)aoff);
    if ((u32)(y1 + dy) < 32u && (u32)(x1 + dx) < 32u)
      v1 = *reinterpret_cast<const u32x4*>(aSrc1 + (ptrdiff_t)aoff);
    u32x4 vb = *reinterpret_cast<const u32x4*>(bSrc + kt * 32);
    *reinterpret_cast<u32x4*>(aDst0) = v0;
    *reinterpret_cast<u32x4*>(aDst1) = v1;
    *reinterpret_cast<u32x4*>(bDst) = vb;
    __syncthreads();
    int ko = (lane >> 4) * 8;
    bf16x8 af[4], bfr[2];
#pragma unroll
    for (int mt = 0; mt < 4; mt++)
      af[mt] = *reinterpret_cast<const bf16x8*>(&As[(wm * 64 + mt * 16 + (lane & 15)) * 40 + ko]);
#pragma unroll
    for (int nt = 0; nt < 2; nt++)
      bfr[nt] = *reinterpret_cast<const bf16x8*>(&Bs[(wn * 32 + nt * 16 + (lane & 15)) * 40 + ko]);
#pragma unroll
    for (int mt = 0; mt < 4; mt++)
#pragma unroll
      for (int nt = 0; nt < 2; nt++)
        acc[mt][nt] = __builtin_amdgcn_mfma_f32_16x16x32_bf16(af[mt], bfr[nt], acc[mt][nt], 0, 0, 0);
  }
#pragma unroll
  for (int mt = 0; mt < 4; mt++) {
#pragma unroll
    for (int nt = 0; nt < 2; nt++) {
      int col = Nbase + wn * 32 + nt * 16 + (lane & 15);
#pragma unroll
      for (int r = 0; r < 4; r++) {
        int rowp = Mbase + wm * 64 + mt * 16 + (lane >> 4) * 4 + r;
        float v = acc[mt][nt][r];
        if (EPI == 0) {
          float yv = v * c0[col] + c1[col];
          float h = yv / (1.0f + __expf(-yv));
          out0[(size_t)rowp * 256 + col] = f2bf(h);
        } else {
          float rv = v + c0[col];
          if (col < 256) {
            reinterpret_cast<_Float16*>(out0)[(size_t)rowp * 256 + (col & 15) * 16 + (col >> 4)] =
                (_Float16)(rv * 0.125f);
          } else {
            int cT = col - 256;
            if (cT < 48) out1[(size_t)rowp * 64 + (cT & 15) * 4 + (cT >> 4)] = rv;
            else         out1[(size_t)rowp * 64 + (cT & 15) * 4 + 3] = 0.0f;
          }
        }
      }
    }
  }
}

// ------------------------------------------------------------- attention ----
// One block (4 waves) per patch. Wave w handles pixel rows py=w*4..w*4+3.
// scores via mfma_f32_16x16x32_f16: A[px][k]=f16(f[c=k&15]), B[k][nl]=r4 (k-dup,
// 0.5 comp folded into rbuf's 0.125 pre-scale). C/D: row=px=(l>>4)*4+reg, col=nl.
__global__ __launch_bounds__(256) void attn_kernel(
    const float* __restrict__ f, const _Float16* __restrict__ rbuf,
    const float* __restrict__ tbuf, float* __restrict__ out)
{
  const size_t cs = (size_t)496 * 496;
  int blk = blockIdx.x;
  int b = blk / 961, rem = blk - b * 961;
  int i = rem / 31, j = rem - i * 31;
  int t = threadIdx.x;
  int lane = t & 63, w = t >> 6;
  int q = lane >> 4, nl = lane & 15;

  f16x8 bfr[4]; float4 tq[4];
#pragma unroll
  for (int g = 0; g < 4; g++) {
    int ii = i + (g & 1), jj = j + (g >> 1);
    int pix = (b * 32 + ii) * 32 + jj;
    bfr[g] = *reinterpret_cast<const f16x8*>(rbuf + (size_t)pix * 256 + nl * 16 + (q & 1) * 8);
    tq[g] = reinterpret_cast<const float4*>(tbuf)[(size_t)pix * 16 + nl];
  }
  const float* fbase = f + ((size_t)b * 16 + (q & 1) * 8) * cs + (size_t)(i * 16) * 496 + j * 16 + nl;

#pragma unroll
  for (int mt = 0; mt < 4; mt++) {
    int py = w * 4 + mt;
    const float* fp = fbase + (size_t)py * 496;
    f16x8 afr;
#pragma unroll
    for (int c = 0; c < 8; c++) afr[c] = (_Float16)fp[(size_t)c * cs];
    f32x4 zero = {0.f, 0.f, 0.f, 0.f};
    f32x4 a0 = __builtin_amdgcn_mfma_f32_16x16x32_f16(afr, bfr[0], zero, 0, 0, 0);
    f32x4 a1 = __builtin_amdgcn_mfma_f32_16x16x32_f16(afr, bfr[1], zero, 0, 0, 0);
    f32x4 a2 = __builtin_amdgcn_mfma_f32_16x16x32_f16(afr, bfr[2], zero, 0, 0, 0);
    f32x4 a3 = __builtin_amdgcn_mfma_f32_16x16x32_f16(afr, bfr[3], zero, 0, 0, 0);
    float ls[4], yo0[4], yo1[4], yo2[4];
#pragma unroll
    for (int r = 0; r < 4; r++) {
      float e0 = __expf(a0[r]), e1 = __expf(a1[r]),
            e2 = __expf(a2[r]), e3 = __expf(a3[r]);
      ls[r]  = (e0 + e1) + (e2 + e3);
      yo0[r] = e0 * tq[0].x + e1 * tq[1].x + e2 * tq[2].x + e3 * tq[3].x;
      yo1[r] = e0 * tq[0].y + e1 * tq[1].y + e2 * tq[2].y + e3 * tq[3].y;
      yo2[r] = e0 * tq[0].z + e1 * tq[1].z + e2 * tq[2].z + e3 * tq[3].z;
    }
#pragma unroll
    for (int m2 = 1; m2 < 16; m2 <<= 1) {
#pragma unroll
      for (int r = 0; r < 4; r++) {
        ls[r]  += __shfl_xor(ls[r],  m2);
        yo0[r] += __shfl_xor(yo0[r], m2);
        yo1[r] += __shfl_xor(yo1[r], m2);
        yo2[r] += __shfl_xor(yo2[r], m2);
      }
    }
    if (nl < 3) {
      float* op = out + ((size_t)b * 3 + nl) * cs + (size_t)(i * 16 + py) * 496 + j * 16 + q * 4;
#pragma unroll
      for (int r = 0; r < 4; r++) {
        float yv = (nl == 0) ? yo0[r] : ((nl == 1) ? yo1[r] : yo2[r]);
        op[r] = yv * __builtin_amdgcn_rcpf(ls[r]);
      }
    }
  }
}

// ----------------------------------------------------------------- launch ---
extern "C" void kernel_launch(void* const* d_in, const int* in_sizes, int n_in,
                              void* d_out, int out_size, void* d_ws, size_t ws_size,
                              hipStream_t stream)
{
  const float* f    = (const float*)d_in[0];
  const float* feats= (const float*)d_in[1];
  const float* wR1  = (const float*)d_in[2];
  const float* bR1  = (const float*)d_in[3];
  const float* gR   = (const float*)d_in[4];
  const float* betR = (const float*)d_in[5];
  const float* mR   = (const float*)d_in[6];
  const float* vR   = (const float*)d_in[7];
  const float* wR2  = (const float*)d_in[8];
  const float* bR2  = (const float*)d_in[9];
  const float* wT1  = (const float*)d_in[10];
  const float* bT1  = (const float*)d_in[11];
  const float* gT   = (const float*)d_in[12];
  const float* betT = (const float*)d_in[13];
  const float* mT   = (const float*)d_in[14];
  const float* vT   = (const float*)d_in[15];
  const float* wT2  = (const float*)d_in[16];
  const float* bT2  = (const float*)d_in[17];
  (void)in_sizes; (void)n_in; (void)out_size; (void)ws_size;

  char* ws = (char*)d_ws;
  u16*   wb1    = (u16*)(ws + 0);              // 256*1152*2 = 589824
  u16*   wb2    = (u16*)(ws + 589824);         // 320*1152*2 = 737280
  float* scale1 = (float*)(ws + 1327104);      // 256 f
  float* shift1 = scale1 + 256;
  float* biasC  = scale1 + 512;                // 320 f
  u16*   feat_t = (u16*)(ws + 1330432);        // 8*1024*128*2 = 2097152
  u16*   hbuf   = (u16*)(ws + 3427584);        // 8192*256*2   = 4194304
  u16*   rbuf16 = (u16*)(ws + 7621888);        // 8192*256*2   = 4194304 (f16)
  float* tbuf   = (float*)(ws + 11816192);     // 8192*64*4    = 2097152

  repack_kernel<<<dim3(2593), dim3(256), 0, stream>>>(
      wR1, wT1, wR2, wT2, bR1, gR, betR, mR, vR, bT1, gT, betT, mT, vT,
      bR2, bT2, wb1, wb2, scale1, shift1, biasC);

  transpose_kernel<<<dim3(256), dim3(256), 0, stream>>>(feats, feat_t);

  conv_gemm_kernel<128, 0><<<dim3(64, 4), dim3(256), 0, stream>>>(
      feat_t, wb1, hbuf, nullptr, scale1, shift1);

  conv_gemm_kernel<256, 1><<<dim3(64, 5), dim3(256), 0, stream>>>(
      hbuf, wb2, rbuf16, tbuf, biasC, nullptr);

  attn_kernel<<<dim3(7688), dim3(256), 0, stream>>>(
      f, (const _Float16*)rbuf16, tbuf, (float*)d_out);
}

// Round 5
// 291.313 us; speedup vs baseline: 1.3447x; 1.0986x over previous
//
#include <hip/hip_runtime.h>
#include <hip/hip_bf16.h>
#include <stdint.h>
#include <stddef.h>

using u32 = unsigned int;
using u16 = unsigned short;

typedef short bf16x8 __attribute__((ext_vector_type(8)));
typedef _Float16 f16x8 __attribute__((ext_vector_type(8)));
typedef float f32x4 __attribute__((ext_vector_type(4)));
typedef u32  u32x4 __attribute__((ext_vector_type(4)));

// 0.25 (1/sqrt(C)) * 0.5 (k-dup comp) * log2(e)  — folded into rbuf
#define RSCALE 0.18033688011112042f

__device__ __forceinline__ u16 f2bf(float f) {
  u32 u = __builtin_bit_cast(u32, f);
  u32 r = (u + 0x7FFFu + ((u >> 16) & 1u)) >> 16;   // RNE
  return (u16)r;
}

// ---------------------------------------------------------------- repack ----
__global__ __launch_bounds__(256) void repack_kernel(
    const float* wR1, const float* wT1, const float* wR2, const float* wT2,
    const float* bR1, const float* gR, const float* betR, const float* mR, const float* vR,
    const float* bT1, const float* gT, const float* betT, const float* mT, const float* vT,
    const float* bR2, const float* bT2,
    u16* wb1, u16* wb2, float* scale1, float* shift1, float* biasC)
{
  if (blockIdx.x == 2592) {
    int t = threadIdx.x;
    float g, v, be, mm, bb;
    if (t < 128) { g = gR[t]; v = vR[t]; be = betR[t]; mm = mR[t]; bb = bR1[t]; }
    else         { g = gT[t-128]; v = vT[t-128]; be = betT[t-128]; mm = mT[t-128]; bb = bT1[t-128]; }
    float sc = g * rsqrtf(v + 1e-5f);
    scale1[t] = sc;
    shift1[t] = (bb - mm) * sc + be;
    biasC[t] = bR2[t];
    if (t < 64) biasC[256 + t] = (t < 48) ? bT2[t] : 0.0f;
    return;
  }
  int idx = blockIdx.x * 256 + threadIdx.x;
  if (idx < 294912) {
    int oc = idx / 1152, k = idx - oc * 1152;
    int tap = k >> 7, ic = k & 127;
    float w = (oc < 128) ? wR1[(oc * 128 + ic) * 9 + tap]
                         : wT1[((oc - 128) * 128 + ic) * 9 + tap];
    wb1[idx] = f2bf(w);
  } else {
    int r2 = idx - 294912;
    int oc = r2 / 1152, k = r2 - oc * 1152;
    int tap = k >> 7, ic = k & 127;
    float w;
    if (oc < 256)            w = wR2[(oc * 128 + ic) * 9 + tap];
    else if (oc - 256 < 48)  w = wT2[((oc - 256) * 128 + ic) * 9 + tap];
    else                     w = 0.0f;
    wb2[r2] = f2bf(w);
  }
}

// ------------------------------------------------------ NCHW -> NHWC bf16 ---
__global__ __launch_bounds__(256) void transpose_kernel(const float* feat, u16* feat_t)
{
  __shared__ float tile[128 * 33];
  int b = blockIdx.x >> 5, y = blockIdx.x & 31;
  int t = threadIdx.x;
  const float* src = feat + (size_t)(b * 128) * 1024 + y * 32;
#pragma unroll
  for (int q = 0; q < 16; q++) {
    int idx = q * 256 + t;
    int ic = idx >> 5, x = idx & 31;
    tile[ic * 33 + x] = src[(size_t)ic * 1024 + x];
  }
  __syncthreads();
  u16* dst = feat_t + (size_t)((b * 32 + y) * 32) * 128;
#pragma unroll
  for (int q = 0; q < 16; q++) {
    int idx = q * 256 + t;
    int x = idx >> 7, ic = idx & 127;
    dst[x * 128 + ic] = f2bf(tile[ic * 33 + x]);
  }
}

// -------------------------------------------- implicit-im2col conv GEMM ----
// LDS layout [k-slot][row]: slot*rows*8 + row*8 halfwords. Reads 2-way (free).
// Register-prefetch double buffer hides global latency (T3 minimal 2-phase).
template <int SRCC, int EPI>
__global__ __launch_bounds__(256) void conv_gemm_kernel(
    const u16* __restrict__ src, const u16* __restrict__ Bt,
    u16* __restrict__ out0, float* __restrict__ out1,
    const float* __restrict__ c0, const float* __restrict__ c1)
{
  __shared__ u16 As[4 * 128 * 8];
  __shared__ u16 Bs[4 * 64 * 8];
  int t = threadIdx.x;
  int lane = t & 63, wid = t >> 6;
  int wm = wid >> 1, wn = wid & 1;
  int Mbase = blockIdx.x * 128, Nbase = blockIdx.y * 64;
  int icOff = (EPI == 1 && blockIdx.y == 4) ? 128 : 0;

  int rA = t >> 2, kc = t & 3;
  int p0 = Mbase + rA, p1 = p0 + 64;
  int y0 = (p0 >> 5) & 31, x0 = p0 & 31;
  int y1 = (p1 >> 5) & 31, x1 = p1 & 31;
  const u16* aSrc0 = src + (size_t)p0 * SRCC + icOff + kc * 8;
  const u16* aSrc1 = src + (size_t)p1 * SRCC + icOff + kc * 8;
  const u16* bSrc  = Bt + (size_t)(Nbase + rA) * 1152 + kc * 8;
  u16* aDst0 = &As[kc * 1024 + rA * 8];
  u16* aDst1 = &As[kc * 1024 + (rA + 64) * 8];
  u16* bDst  = &Bs[kc * 512 + rA * 8];

  u32x4 v0, v1, vb;
  auto LOADK = [&](int kt) {
    int tap = kt >> 2;
    int dy = tap / 3 - 1, dx = tap - (tap / 3) * 3 - 1;
    int aoff = (dy * 32 + dx) * SRCC + (kt & 3) * 32;
    u32x4 z = {};
    v0 = z; v1 = z;
    if ((u32)(y0 + dy) < 32u && (u32)(x0 + dx) < 32u)
      v0 = *reinterpret_cast<const u32x4*>(aSrc0 + (ptrdiff_t)aoff);
    if ((u32)(y1 + dy) < 32u && (u32)(x1 + dx) < 32u)
      v1 = *reinterpret_cast<const u32x4*>(aSrc1 + (ptrdiff_t)aoff);
    vb = *reinterpret_cast<const u32x4*>(bSrc + kt * 32);
  };

  f32x4 acc[4][2] = {};
  LOADK(0);
  int L = lane & 15, qs = lane >> 4;
  for (int kt = 0; kt < 36; kt++) {
    __syncthreads();
    *reinterpret_cast<u32x4*>(aDst0) = v0;
    *reinterpret_cast<u32x4*>(aDst1) = v1;
    *reinterpret_cast<u32x4*>(bDst)  = vb;
    if (kt < 35) LOADK(kt + 1);
    __syncthreads();
    bf16x8 af[4], bfr2[2];
#pragma unroll
    for (int mt = 0; mt < 4; mt++)
      af[mt] = *reinterpret_cast<const bf16x8*>(&As[qs * 1024 + (wm * 64 + mt * 16 + L) * 8]);
#pragma unroll
    for (int nt = 0; nt < 2; nt++)
      bfr2[nt] = *reinterpret_cast<const bf16x8*>(&Bs[qs * 512 + (wn * 32 + nt * 16 + L) * 8]);
#pragma unroll
    for (int mt = 0; mt < 4; mt++)
#pragma unroll
      for (int nt = 0; nt < 2; nt++)
        acc[mt][nt] = __builtin_amdgcn_mfma_f32_16x16x32_bf16(af[mt], bfr2[nt], acc[mt][nt], 0, 0, 0);
  }
#pragma unroll
  for (int mt = 0; mt < 4; mt++) {
#pragma unroll
    for (int nt = 0; nt < 2; nt++) {
      int col = Nbase + wn * 32 + nt * 16 + (lane & 15);
#pragma unroll
      for (int r = 0; r < 4; r++) {
        int rowp = Mbase + wm * 64 + mt * 16 + (lane >> 4) * 4 + r;
        float v = acc[mt][nt][r];
        if (EPI == 0) {
          float yv = v * c0[col] + c1[col];
          float h = yv / (1.0f + __expf(-yv));
          out0[(size_t)rowp * 256 + col] = f2bf(h);
        } else {
          float rv = v + c0[col];
          if (col < 256) {
            reinterpret_cast<_Float16*>(out0)[(size_t)rowp * 256 + (col & 15) * 16 + (col >> 4)] =
                (_Float16)(rv * RSCALE);
          } else {
            int cT = col - 256;
            if (cT < 48) out1[(size_t)rowp * 64 + (cT & 15) * 4 + (cT >> 4)] = rv;
            else         out1[(size_t)rowp * 64 + (cT & 15) * 4 + 3] = 0.0f;
          }
        }
      }
    }
  }
}

// ------------------------------------------------------------- attention ----
// Swapped QK^T: mfma(A=r4, B=f) -> lane (q,nl) holds scores for pixel px=nl,
// colors {g*16 + q*4 + r}. Softmax+PV in-lane over 16 colors; 2-step cross-q
// reduce (xor16/xor32). f staged to LDS as f16 [py][h][px^py][8ch].
__global__ __launch_bounds__(256) void attn_kernel(
    const float* __restrict__ f, const _Float16* __restrict__ rbuf,
    const float4* __restrict__ tbuf, float* __restrict__ out)
{
  const size_t cs = (size_t)496 * 496;
  __shared__ u16 fl[4096];
  int blk = blockIdx.x;
  int b = blk / 961, rem = blk - b * 961;
  int i = rem / 31, j = rem - i * 31;
  int t = threadIdx.x;
  int lane = t & 63, w = t >> 6;
  int q = lane >> 4, nl = lane & 15;

  // ---- stage f (16ch x 16x16) -> LDS f16 ----
  {
    int a = t >> 5;            // channel pair (2a, 2a+1)
    int spy = (t >> 1) & 15;
    int half = t & 1;
    const float* fb = f + ((size_t)b * 16 + 2 * a) * cs
                        + (size_t)(i * 16 + spy) * 496 + j * 16 + half * 8;
    float4 c0a = *reinterpret_cast<const float4*>(fb);
    float4 c0b = *reinterpret_cast<const float4*>(fb + 4);
    float4 c1a = *reinterpret_cast<const float4*>(fb + cs);
    float4 c1b = *reinterpret_cast<const float4*>(fb + cs + 4);
    float lo[8] = {c0a.x, c0a.y, c0a.z, c0a.w, c0b.x, c0b.y, c0b.z, c0b.w};
    float hi[8] = {c1a.x, c1a.y, c1a.z, c1a.w, c1b.x, c1b.y, c1b.z, c1b.w};
    int base = spy * 256 + (a >> 2) * 128 + (a & 3) * 2;
#pragma unroll
    for (int p = 0; p < 8; p++) {
      int px = half * 8 + p;
      u32 pk = __builtin_bit_cast(u32, __builtin_amdgcn_cvt_pkrtz(lo[p], hi[p]));
      *reinterpret_cast<u32*>(&fl[base + ((px ^ spy) * 8)]) = pk;
    }
  }

  // ---- per-lane constants: r4 A-fragments + t triples ----
  f16x8 bfr[4];
  float tx[16], ty[16], tz[16];
#pragma unroll
  for (int g = 0; g < 4; g++) {
    int ii = i + (g & 1), jj = j + (g >> 1);
    int pix = (b * 32 + ii) * 32 + jj;
    bfr[g] = *reinterpret_cast<const f16x8*>(rbuf + (size_t)pix * 256 + nl * 16 + (q & 1) * 8);
#pragma unroll
    for (int r = 0; r < 4; r++) {
      float4 tv = tbuf[(size_t)pix * 16 + q * 4 + r];
      tx[g * 4 + r] = tv.x; ty[g * 4 + r] = tv.y; tz[g * 4 + r] = tv.z;
    }
  }
  __syncthreads();

#pragma unroll
  for (int mt = 0; mt < 4; mt++) {
    int py = w * 4 + mt;
    f16x8 afr = *reinterpret_cast<const f16x8*>(&fl[py * 256 + (q & 1) * 128 + ((nl ^ py) & 15) * 8]);
    f32x4 z = {0.f, 0.f, 0.f, 0.f};
    f32x4 s0 = __builtin_amdgcn_mfma_f32_16x16x32_f16(bfr[0], afr, z, 0, 0, 0);
    f32x4 s1 = __builtin_amdgcn_mfma_f32_16x16x32_f16(bfr[1], afr, z, 0, 0, 0);
    f32x4 s2 = __builtin_amdgcn_mfma_f32_16x16x32_f16(bfr[2], afr, z, 0, 0, 0);
    f32x4 s3 = __builtin_amdgcn_mfma_f32_16x16x32_f16(bfr[3], afr, z, 0, 0, 0);

    float pm = s0[0];
#pragma unroll
    for (int r = 0; r < 4; r++) {
      pm = fmaxf(pm, s0[r]); pm = fmaxf(pm, s1[r]);
      pm = fmaxf(pm, s2[r]); pm = fmaxf(pm, s3[r]);
    }
    pm = fmaxf(pm, __shfl_xor(pm, 16));
    pm = fmaxf(pm, __shfl_xor(pm, 32));

    float l = 0.f, o0 = 0.f, o1 = 0.f, o2 = 0.f;
#pragma unroll
    for (int r = 0; r < 4; r++) {
      float e0 = exp2f(s0[r] - pm), e1 = exp2f(s1[r] - pm),
            e2 = exp2f(s2[r] - pm), e3 = exp2f(s3[r] - pm);
      l  += (e0 + e1) + (e2 + e3);
      o0 += e0 * tx[r] + e1 * tx[4 + r] + e2 * tx[8 + r] + e3 * tx[12 + r];
      o1 += e0 * ty[r] + e1 * ty[4 + r] + e2 * ty[8 + r] + e3 * ty[12 + r];
      o2 += e0 * tz[r] + e1 * tz[4 + r] + e2 * tz[8 + r] + e3 * tz[12 + r];
    }
    l  += __shfl_xor(l, 16);  l  += __shfl_xor(l, 32);
    o0 += __shfl_xor(o0, 16); o0 += __shfl_xor(o0, 32);
    o1 += __shfl_xor(o1, 16); o1 += __shfl_xor(o1, 32);
    o2 += __shfl_xor(o2, 16); o2 += __shfl_xor(o2, 32);

    if (q < 3) {
      float yv = (q == 0) ? o0 : ((q == 1) ? o1 : o2);
      out[((size_t)b * 3 + q) * cs + (size_t)(i * 16 + py) * 496 + j * 16 + nl] =
          yv * __builtin_amdgcn_rcpf(l);
    }
  }
}

// ----------------------------------------------------------------- launch ---
extern "C" void kernel_launch(void* const* d_in, const int* in_sizes, int n_in,
                              void* d_out, int out_size, void* d_ws, size_t ws_size,
                              hipStream_t stream)
{
  const float* f    = (const float*)d_in[0];
  const float* feats= (const float*)d_in[1];
  const float* wR1  = (const float*)d_in[2];
  const float* bR1  = (const float*)d_in[3];
  const float* gR   = (const float*)d_in[4];
  const float* betR = (const float*)d_in[5];
  const float* mR   = (const float*)d_in[6];
  const float* vR   = (const float*)d_in[7];
  const float* wR2  = (const float*)d_in[8];
  const float* bR2  = (const float*)d_in[9];
  const float* wT1  = (const float*)d_in[10];
  const float* bT1  = (const float*)d_in[11];
  const float* gT   = (const float*)d_in[12];
  const float* betT = (const float*)d_in[13];
  const float* mT   = (const float*)d_in[14];
  const float* vT   = (const float*)d_in[15];
  const float* wT2  = (const float*)d_in[16];
  const float* bT2  = (const float*)d_in[17];
  (void)in_sizes; (void)n_in; (void)out_size; (void)ws_size;

  char* ws = (char*)d_ws;
  u16*   wb1    = (u16*)(ws + 0);              // 256*1152*2 = 589824
  u16*   wb2    = (u16*)(ws + 589824);         // 320*1152*2 = 737280
  float* scale1 = (float*)(ws + 1327104);      // 256 f
  float* shift1 = scale1 + 256;
  float* biasC  = scale1 + 512;                // 320 f
  u16*   feat_t = (u16*)(ws + 1330432);        // 8*1024*128*2 = 2097152
  u16*   hbuf   = (u16*)(ws + 3427584);        // 8192*256*2   = 4194304
  u16*   rbuf16 = (u16*)(ws + 7621888);        // 8192*256*2   = 4194304 (f16)
  float* tbuf   = (float*)(ws + 11816192);     // 8192*64*4    = 2097152

  repack_kernel<<<dim3(2593), dim3(256), 0, stream>>>(
      wR1, wT1, wR2, wT2, bR1, gR, betR, mR, vR, bT1, gT, betT, mT, vT,
      bR2, bT2, wb1, wb2, scale1, shift1, biasC);

  transpose_kernel<<<dim3(256), dim3(256), 0, stream>>>(feats, feat_t);

  conv_gemm_kernel<128, 0><<<dim3(64, 4), dim3(256), 0, stream>>>(
      feat_t, wb1, hbuf, nullptr, scale1, shift1);

  conv_gemm_kernel<256, 1><<<dim3(64, 5), dim3(256), 0, stream>>>(
      hbuf, wb2, rbuf16, tbuf, biasC, nullptr);

  attn_kernel<<<dim3(7688), dim3(256), 0, stream>>>(
      f, (const _Float16*)rbuf16, (const float4*)tbuf, (float*)d_out);
}

// Round 6
// 278.936 us; speedup vs baseline: 1.4044x; 1.0444x over previous
//
#include <hip/hip_runtime.h>
#include <hip/hip_bf16.h>
#include <stdint.h>
#include <stddef.h>

using u32 = unsigned int;
using u16 = unsigned short;

typedef short bf16x8 __attribute__((ext_vector_type(8)));
typedef _Float16 f16x8 __attribute__((ext_vector_type(8)));
typedef float f32x4 __attribute__((ext_vector_type(4)));
typedef u32  u32x4 __attribute__((ext_vector_type(4)));
typedef u32  u32x2 __attribute__((ext_vector_type(2)));

// 0.25 (1/sqrt(C)) * 0.5 (k-dup comp) * log2(e)  — folded into rbuf
#define RSCALE 0.18033688011112042f

__device__ __forceinline__ u16 f2bf(float f) {
  u32 u = __builtin_bit_cast(u32, f);
  u32 r = (u + 0x7FFFu + ((u >> 16) & 1u)) >> 16;   // RNE
  return (u16)r;
}

__device__ __forceinline__ u32 pkh(float a, float b) {
  return __builtin_bit_cast(u32, __builtin_amdgcn_cvt_pkrtz(a, b));
}

// ---------------------------------------------------------------- repack ----
__global__ __launch_bounds__(256) void repack_kernel(
    const float* wR1, const float* wT1, const float* wR2, const float* wT2,
    const float* bR1, const float* gR, const float* betR, const float* mR, const float* vR,
    const float* bT1, const float* gT, const float* betT, const float* mT, const float* vT,
    const float* bR2, const float* bT2,
    u16* wb1, u16* wb2, float* scale1, float* shift1, float* biasC)
{
  if (blockIdx.x == 2592) {
    int t = threadIdx.x;
    float g, v, be, mm, bb;
    if (t < 128) { g = gR[t]; v = vR[t]; be = betR[t]; mm = mR[t]; bb = bR1[t]; }
    else         { g = gT[t-128]; v = vT[t-128]; be = betT[t-128]; mm = mT[t-128]; bb = bT1[t-128]; }
    float sc = g * rsqrtf(v + 1e-5f);
    scale1[t] = sc;
    shift1[t] = (bb - mm) * sc + be;
    biasC[t] = bR2[t];
    if (t < 64) biasC[256 + t] = (t < 48) ? bT2[t] : 0.0f;
    return;
  }
  int idx = blockIdx.x * 256 + threadIdx.x;
  if (idx < 294912) {
    int oc = idx / 1152, k = idx - oc * 1152;
    int tap = k >> 7, ic = k & 127;
    float w = (oc < 128) ? wR1[(oc * 128 + ic) * 9 + tap]
                         : wT1[((oc - 128) * 128 + ic) * 9 + tap];
    wb1[idx] = f2bf(w);
  } else {
    int r2 = idx - 294912;
    int oc = r2 / 1152, k = r2 - oc * 1152;
    int tap = k >> 7, ic = k & 127;
    float w;
    if (oc < 256)            w = wR2[(oc * 128 + ic) * 9 + tap];
    else if (oc - 256 < 48)  w = wT2[((oc - 256) * 128 + ic) * 9 + tap];
    else                     w = 0.0f;
    wb2[r2] = f2bf(w);
  }
}

// ------------------------------------------------------ NCHW -> NHWC bf16 ---
__global__ __launch_bounds__(256) void transpose_kernel(const float* feat, u16* feat_t)
{
  __shared__ float tile[128 * 33];
  int b = blockIdx.x >> 5, y = blockIdx.x & 31;
  int t = threadIdx.x;
  const float* src = feat + (size_t)(b * 128) * 1024 + y * 32;
#pragma unroll
  for (int q = 0; q < 16; q++) {
    int idx = q * 256 + t;
    int ic = idx >> 5, x = idx & 31;
    tile[ic * 33 + x] = src[(size_t)ic * 1024 + x];
  }
  __syncthreads();
  u16* dst = feat_t + (size_t)((b * 32 + y) * 32) * 128;
#pragma unroll
  for (int q = 0; q < 16; q++) {
    int idx = q * 256 + t;
    int x = idx >> 7, ic = idx & 127;
    dst[x * 128 + ic] = f2bf(tile[ic * 33 + x]);
  }
}

// -------------------------------------------- implicit-im2col conv GEMM ----
template <int SRCC, int EPI>
__global__ __launch_bounds__(256) void conv_gemm_kernel(
    const u16* __restrict__ src, const u16* __restrict__ Bt,
    u16* __restrict__ out0, float* __restrict__ out1,
    const float* __restrict__ c0, const float* __restrict__ c1)
{
  __shared__ u16 As[4 * 128 * 8];
  __shared__ u16 Bs[4 * 64 * 8];
  int t = threadIdx.x;
  int lane = t & 63, wid = t >> 6;
  int wm = wid >> 1, wn = wid & 1;
  int Mbase = blockIdx.x * 128, Nbase = blockIdx.y * 64;
  int icOff = (EPI == 1 && blockIdx.y == 4) ? 128 : 0;

  int rA = t >> 2, kc = t & 3;
  int p0 = Mbase + rA, p1 = p0 + 64;
  int y0 = (p0 >> 5) & 31, x0 = p0 & 31;
  int y1 = (p1 >> 5) & 31, x1 = p1 & 31;
  const u16* aSrc0 = src + (size_t)p0 * SRCC + icOff + kc * 8;
  const u16* aSrc1 = src + (size_t)p1 * SRCC + icOff + kc * 8;
  const u16* bSrc  = Bt + (size_t)(Nbase + rA) * 1152 + kc * 8;
  u16* aDst0 = &As[kc * 1024 + rA * 8];
  u16* aDst1 = &As[kc * 1024 + (rA + 64) * 8];
  u16* bDst  = &Bs[kc * 512 + rA * 8];

  u32x4 v0, v1, vb;
  auto LOADK = [&](int kt) {
    int tap = kt >> 2;
    int dy = tap / 3 - 1, dx = tap - (tap / 3) * 3 - 1;
    int aoff = (dy * 32 + dx) * SRCC + (kt & 3) * 32;
    u32x4 z = {};
    v0 = z; v1 = z;
    if ((u32)(y0 + dy) < 32u && (u32)(x0 + dx) < 32u)
      v0 = *reinterpret_cast<const u32x4*>(aSrc0 + (ptrdiff_t)aoff);
    if ((u32)(y1 + dy) < 32u && (u32)(x1 + dx) < 32u)
      v1 = *reinterpret_cast<const u32x4*>(aSrc1 + (ptrdiff_t)aoff);
    vb = *reinterpret_cast<const u32x4*>(bSrc + kt * 32);
  };

  f32x4 acc[4][2] = {};
  LOADK(0);
  int L = lane & 15, qs = lane >> 4;
  for (int kt = 0; kt < 36; kt++) {
    __syncthreads();
    *reinterpret_cast<u32x4*>(aDst0) = v0;
    *reinterpret_cast<u32x4*>(aDst1) = v1;
    *reinterpret_cast<u32x4*>(bDst)  = vb;
    if (kt < 35) LOADK(kt + 1);
    __syncthreads();
    bf16x8 af[4], bfr2[2];
#pragma unroll
    for (int mt = 0; mt < 4; mt++)
      af[mt] = *reinterpret_cast<const bf16x8*>(&As[qs * 1024 + (wm * 64 + mt * 16 + L) * 8]);
#pragma unroll
    for (int nt = 0; nt < 2; nt++)
      bfr2[nt] = *reinterpret_cast<const bf16x8*>(&Bs[qs * 512 + (wn * 32 + nt * 16 + L) * 8]);
#pragma unroll
    for (int mt = 0; mt < 4; mt++)
#pragma unroll
      for (int nt = 0; nt < 2; nt++)
        acc[mt][nt] = __builtin_amdgcn_mfma_f32_16x16x32_bf16(af[mt], bfr2[nt], acc[mt][nt], 0, 0, 0);
  }
#pragma unroll
  for (int mt = 0; mt < 4; mt++) {
#pragma unroll
    for (int nt = 0; nt < 2; nt++) {
      int col = Nbase + wn * 32 + nt * 16 + (lane & 15);
#pragma unroll
      for (int r = 0; r < 4; r++) {
        int rowp = Mbase + wm * 64 + mt * 16 + (lane >> 4) * 4 + r;
        float v = acc[mt][nt][r];
        if (EPI == 0) {
          float yv = v * c0[col] + c1[col];
          float h = yv / (1.0f + __expf(-yv));
          out0[(size_t)rowp * 256 + col] = f2bf(h);
        } else {
          float rv = v + c0[col];
          if (col < 256) {
            reinterpret_cast<_Float16*>(out0)[(size_t)rowp * 256 + (col & 15) * 16 + (col >> 4)] =
                (_Float16)(rv * RSCALE);
          } else {
            int cT = col - 256;
            if (cT < 48) out1[(size_t)rowp * 64 + (cT & 15) * 4 + (cT >> 4)] = rv;
            else         out1[(size_t)rowp * 64 + (cT & 15) * 4 + 3] = 0.0f;
          }
        }
      }
    }
  }
}

// ------------------------------------------------------------- attention ----
// QK^T swapped: lane (q,nl) holds s[color w=q*4+r of group g][px=nl].
// Logical color perm: L(g,w) = q*8 + (g&1)*4 + r + (g>>1)*32  (softmax is
// order-invariant) -> exp values are exactly the A-fragments of two
// mfma_f32_16x16x32_f16 PV matmuls (K=64). B = t table in LDS [c][L], with
// column c=3 = 1.0 so the same MFMA produces the softmax denominator l.
// No max-subtraction: |s_log2| <= ~10 << 44 needed for overflow.
__global__ __launch_bounds__(256) void attn_kernel(
    const float* __restrict__ f, const _Float16* __restrict__ rbuf,
    const float4* __restrict__ tbuf, float* __restrict__ out)
{
  const size_t cs = (size_t)496 * 496;
  __shared__ u16 fl[4096];      // 8KB staged f (f16)
  __shared__ u16 tl[1024];      // 2KB PV B-table [c][L] (f16)
  int blk = blockIdx.x;
  int b = blk / 961, rem = blk - b * 961;
  int i = rem / 31, j = rem - i * 31;
  int t = threadIdx.x;
  int lane = t & 63, w = t >> 6;
  int q = lane >> 4, nl = lane & 15;

  // ---- stage f (16ch x 16x16) -> LDS f16 ----
  {
    int a = t >> 5;            // channel pair (2a, 2a+1)
    int spy = (t >> 1) & 15;
    int half = t & 1;
    const float* fb = f + ((size_t)b * 16 + 2 * a) * cs
                        + (size_t)(i * 16 + spy) * 496 + j * 16 + half * 8;
    float4 c0a = *reinterpret_cast<const float4*>(fb);
    float4 c0b = *reinterpret_cast<const float4*>(fb + 4);
    float4 c1a = *reinterpret_cast<const float4*>(fb + cs);
    float4 c1b = *reinterpret_cast<const float4*>(fb + cs + 4);
    float lo[8] = {c0a.x, c0a.y, c0a.z, c0a.w, c0b.x, c0b.y, c0b.z, c0b.w};
    float hi[8] = {c1a.x, c1a.y, c1a.z, c1a.w, c1b.x, c1b.y, c1b.z, c1b.w};
    int base = spy * 256 + (a >> 2) * 128 + (a & 3) * 2;
#pragma unroll
    for (int p = 0; p < 8; p++) {
      int px = half * 8 + p;
      *reinterpret_cast<u32*>(&fl[base + ((px ^ spy) * 8)]) = pkh(lo[p], hi[p]);
    }
  }

  // ---- stage t -> tl[c*64 + L] (c=3 -> 1.0, c>3 -> 0) ----
  {
    int c = t & 15, lq = t >> 4;          // lq 0..15, L = lq*4+e2
    float v[4];
#pragma unroll
    for (int e2 = 0; e2 < 4; e2++) {
      int l4 = lq * 4 + e2;
      float vv = 0.0f;
      if (c == 3) vv = 1.0f;
      else if (c < 3) {
        int wcol = ((l4 >> 3) & 3) * 4 + (l4 & 3);
        int g = (l4 >> 5) * 2 + ((l4 >> 2) & 1);
        int ii = i + (g & 1), jj = j + (g >> 1);
        int pix = (b * 32 + ii) * 32 + jj;
        vv = reinterpret_cast<const float*>(&tbuf[(size_t)pix * 16 + wcol])[c];
      }
      v[e2] = vv;
    }
    u32x2 pp = { pkh(v[0], v[1]), pkh(v[2], v[3]) };
    *reinterpret_cast<u32x2*>(&tl[c * 64 + lq * 4]) = pp;
  }

  // ---- per-lane r4 A-fragments ----
  f16x8 bfr[4];
#pragma unroll
  for (int g = 0; g < 4; g++) {
    int ii = i + (g & 1), jj = j + (g >> 1);
    int pix = (b * 32 + ii) * 32 + jj;
    bfr[g] = *reinterpret_cast<const f16x8*>(rbuf + (size_t)pix * 256 + nl * 16 + (q & 1) * 8);
  }
  __syncthreads();

  // PV B-fragments (per-lane, block constants)
  f16x8 pb1 = *reinterpret_cast<const f16x8*>(&tl[nl * 64 + q * 8]);
  f16x8 pb2 = *reinterpret_cast<const f16x8*>(&tl[nl * 64 + 32 + q * 8]);

#pragma unroll
  for (int mt = 0; mt < 4; mt++) {
    int py = w * 4 + mt;
    f16x8 afr = *reinterpret_cast<const f16x8*>(&fl[py * 256 + (q & 1) * 128 + ((nl ^ py) & 15) * 8]);
    f32x4 z = {0.f, 0.f, 0.f, 0.f};
    f32x4 s0 = __builtin_amdgcn_mfma_f32_16x16x32_f16(bfr[0], afr, z, 0, 0, 0);
    f32x4 s1 = __builtin_amdgcn_mfma_f32_16x16x32_f16(bfr[1], afr, z, 0, 0, 0);
    f32x4 s2 = __builtin_amdgcn_mfma_f32_16x16x32_f16(bfr[2], afr, z, 0, 0, 0);
    f32x4 s3 = __builtin_amdgcn_mfma_f32_16x16x32_f16(bfr[3], afr, z, 0, 0, 0);

    float e0[4], e1[4], e2[4], e3[4];
#pragma unroll
    for (int r = 0; r < 4; r++) {
      e0[r] = exp2f(s0[r]); e1[r] = exp2f(s1[r]);
      e2[r] = exp2f(s2[r]); e3[r] = exp2f(s3[r]);
    }
    u32x4 A1u = { pkh(e0[0], e0[1]), pkh(e0[2], e0[3]),
                  pkh(e1[0], e1[1]), pkh(e1[2], e1[3]) };
    u32x4 A2u = { pkh(e2[0], e2[1]), pkh(e2[2], e2[3]),
                  pkh(e3[0], e3[1]), pkh(e3[2], e3[3]) };
    f16x8 A1 = __builtin_bit_cast(f16x8, A1u);
    f16x8 A2 = __builtin_bit_cast(f16x8, A2u);

    f32x4 d = __builtin_amdgcn_mfma_f32_16x16x32_f16(A1, pb1, z, 0, 0, 0);
    d = __builtin_amdgcn_mfma_f32_16x16x32_f16(A2, pb2, d, 0, 0, 0);

    int src = (lane & 48) | 3;          // lane (q,3) holds l[px=q*4+r]
    float l0 = __shfl(d[0], src), l1 = __shfl(d[1], src),
          l2 = __shfl(d[2], src), l3 = __shfl(d[3], src);
    if (nl < 3) {
      float4 o;
      o.x = d[0] * __builtin_amdgcn_rcpf(l0);
      o.y = d[1] * __builtin_amdgcn_rcpf(l1);
      o.z = d[2] * __builtin_amdgcn_rcpf(l2);
      o.w = d[3] * __builtin_amdgcn_rcpf(l3);
      *reinterpret_cast<float4*>(out + ((size_t)b * 3 + nl) * cs
                                 + (size_t)(i * 16 + py) * 496 + j * 16 + q * 4) = o;
    }
  }
}

// ----------------------------------------------------------------- launch ---
extern "C" void kernel_launch(void* const* d_in, const int* in_sizes, int n_in,
                              void* d_out, int out_size, void* d_ws, size_t ws_size,
                              hipStream_t stream)
{
  const float* f    = (const float*)d_in[0];
  const float* feats= (const float*)d_in[1];
  const float* wR1  = (const float*)d_in[2];
  const float* bR1  = (const float*)d_in[3];
  const float* gR   = (const float*)d_in[4];
  const float* betR = (const float*)d_in[5];
  const float* mR   = (const float*)d_in[6];
  const float* vR   = (const float*)d_in[7];
  const float* wR2  = (const float*)d_in[8];
  const float* bR2  = (const float*)d_in[9];
  const float* wT1  = (const float*)d_in[10];
  const float* bT1  = (const float*)d_in[11];
  const float* gT   = (const float*)d_in[12];
  const float* betT = (const float*)d_in[13];
  const float* mT   = (const float*)d_in[14];
  const float* vT   = (const float*)d_in[15];
  const float* wT2  = (const float*)d_in[16];
  const float* bT2  = (const float*)d_in[17];
  (void)in_sizes; (void)n_in; (void)out_size; (void)ws_size;

  char* ws = (char*)d_ws;
  u16*   wb1    = (u16*)(ws + 0);              // 256*1152*2 = 589824
  u16*   wb2    = (u16*)(ws + 589824);         // 320*1152*2 = 737280
  float* scale1 = (float*)(ws + 1327104);      // 256 f
  float* shift1 = scale1 + 256;
  float* biasC  = scale1 + 512;                // 320 f
  u16*   feat_t = (u16*)(ws + 1330432);        // 8*1024*128*2 = 2097152
  u16*   hbuf   = (u16*)(ws + 3427584);        // 8192*256*2   = 4194304
  u16*   rbuf16 = (u16*)(ws + 7621888);        // 8192*256*2   = 4194304 (f16)
  float* tbuf   = (float*)(ws + 11816192);     // 8192*64*4    = 2097152

  repack_kernel<<<dim3(2593), dim3(256), 0, stream>>>(
      wR1, wT1, wR2, wT2, bR1, gR, betR, mR, vR, bT1, gT, betT, mT, vT,
      bR2, bT2, wb1, wb2, scale1, shift1, biasC);

  transpose_kernel<<<dim3(256), dim3(256), 0, stream>>>(feats, feat_t);

  conv_gemm_kernel<128, 0><<<dim3(64, 4), dim3(256), 0, stream>>>(
      feat_t, wb1, hbuf, nullptr, scale1, shift1);

  conv_gemm_kernel<256, 1><<<dim3(64, 5), dim3(256), 0, stream>>>(
      hbuf, wb2, rbuf16, tbuf, biasC, nullptr);

  attn_kernel<<<dim3(7688), dim3(256), 0, stream>>>(
      f, (const _Float16*)rbuf16, (const float4*)tbuf, (float*)d_out);
}